// Round 9
// baseline (580.310 us; speedup 1.0000x reference)
//
#include <hip/hip_runtime.h>

#define NN 163842
#define NE 983040
#define NB 641   // ceil(NN/256)

// ---------------- degree count (int) ----------------
__global__ __launch_bounds__(256) void deg_count(const int* __restrict__ dst,
                                                 int* __restrict__ degi, int E) {
    int e = blockIdx.x * 256 + threadIdx.x;
    if (e < E) atomicAdd(&degi[dst[e]], 1);
}

// ---------------- exclusive scan of degi -> cursor ----------------
__global__ __launch_bounds__(256) void scan1(const int* __restrict__ degi,
                                             int* __restrict__ cursor,
                                             int* __restrict__ bsum, int n) {
    __shared__ int tmp[256];
    int t = threadIdx.x;
    int i = blockIdx.x * 256 + t;
    int v = (i < n) ? degi[i] : 0;
    tmp[t] = v;
    __syncthreads();
    for (int o = 1; o < 256; o <<= 1) {
        int x = (t >= o) ? tmp[t - o] : 0;
        __syncthreads();
        tmp[t] += x;
        __syncthreads();
    }
    if (i < n) cursor[i] = tmp[t] - v;            // exclusive
    if (t == 255) bsum[blockIdx.x] = tmp[255];    // block total
}

__global__ void scan2(int* __restrict__ bsum, int nb) {
    __shared__ int tmp[1024];
    int t = threadIdx.x;
    int v = (t < nb) ? bsum[t] : 0;
    tmp[t] = v;
    __syncthreads();
    for (int o = 1; o < 1024; o <<= 1) {
        int x = (t >= o) ? tmp[t - o] : 0;
        __syncthreads();
        tmp[t] += x;
        __syncthreads();
    }
    if (t < nb) bsum[t] = tmp[t] - v;
}

__global__ __launch_bounds__(256) void scan3(int* __restrict__ cursor,
                                             const int* __restrict__ bsum, int n) {
    int i = blockIdx.x * 256 + threadIdx.x;
    if (i < n) cursor[i] += bsum[blockIdx.x];
}

// ---------------- scatter: permute src / edge_attr into dst-sorted order ----------------
__global__ __launch_bounds__(256) void scatter_k(const int* __restrict__ src,
                                                 const int* __restrict__ dst,
                                                 const float* __restrict__ ea,
                                                 int* __restrict__ cursor,
                                                 int* __restrict__ srcs,
                                                 float2* __restrict__ eas2, int E) {
    int e = blockIdx.x * 256 + threadIdx.x;
    if (e >= E) return;
    int p = atomicAdd(&cursor[dst[e]], 1);
    srcs[p] = src[e];
    eas2[p] = make_float2(ea[2 * e], ea[2 * e + 1]);
}

// ---------------- pad x [N,22] -> xp [N,32] ----------------
__global__ __launch_bounds__(256) void pad_x(const float* __restrict__ x,
                                             float* __restrict__ xp, int n) {
    int t = blockIdx.x * 256 + threadIdx.x;
    if (t >= n * 32) return;
    int r = t >> 5, c = t & 31;
    xp[t] = (c < 22) ? x[r * 22 + c] : 0.0f;
}

// ---------------- gaussians (permuted order), packed float4 ----------------
__global__ __launch_bounds__(256) void gauss_p(const float2* __restrict__ eas2,
                                               const float* __restrict__ mu,
                                               const float* __restrict__ sigma,
                                               float4* __restrict__ gs4, int E) {
    int p = blockIdx.x * 256 + threadIdx.x;
    if (p >= E) return;
    float2 ea = eas2[p];
    float g[3];
#pragma unroll
    for (int k = 0; k < 3; ++k) {
        float d0 = ea.x - mu[2 * k];
        float d1 = ea.y - mu[2 * k + 1];
        float s0 = sigma[2 * k];
        float s1 = sigma[2 * k + 1];
        float q  = d0 * d0 / (1e-15f + s0 * s0) + d1 * d1 / (1e-15f + s1 * s1);
        g[k] = __expf(-0.5f * q);
    }
    gs4[p] = make_float4(g[0], g[1], g[2], 0.0f);
}

static __device__ __forceinline__ void fma4(float4& a, float g, const float4& hv) {
    a.x = fmaf(g, hv.x, a.x);
    a.y = fmaf(g, hv.y, a.y);
    a.z = fmaf(g, hv.z, a.z);
    a.w = fmaf(g, hv.w, a.w);
}

// ---------------- dst-centric segmented aggregation (no atomics, float4, 4x unroll) ----
template <int CINP>
__global__ __launch_bounds__(256) void aggregate4(const float* __restrict__ h, int hs,
                                                  const int* __restrict__ srcs,
                                                  const float4* __restrict__ gs4,
                                                  const int* __restrict__ cursor,
                                                  const int* __restrict__ degi,
                                                  float* __restrict__ S, int n) {
    constexpr int LPN = CINP / 4;                     // lanes per node
    const int c4 = (threadIdx.x % LPN) * 4;
    const int sw = (blockIdx.x * 256 + threadIdx.x) / LPN;
    const int nsw = gridDim.x * (256 / LPN);
    for (int d = sw; d < n; d += nsw) {
        int end = cursor[d];
        int dg  = degi[d];
        int p   = end - dg;
        float4 a0 = {0, 0, 0, 0}, a1 = {0, 0, 0, 0}, a2 = {0, 0, 0, 0};
        for (; p + 4 <= end; p += 4) {
            int s[4];
            float4 g[4], hv[4];
#pragma unroll
            for (int u = 0; u < 4; ++u) s[u] = srcs[p + u];
#pragma unroll
            for (int u = 0; u < 4; ++u) g[u] = gs4[p + u];
#pragma unroll
            for (int u = 0; u < 4; ++u)
                hv[u] = *(const float4*)(h + (long)s[u] * hs + c4);
#pragma unroll
            for (int u = 0; u < 4; ++u) {
                fma4(a0, g[u].x, hv[u]);
                fma4(a1, g[u].y, hv[u]);
                fma4(a2, g[u].z, hv[u]);
            }
        }
        for (; p < end; ++p) {
            int s = srcs[p];
            float4 g = gs4[p];
            float4 hv = *(const float4*)(h + (long)s * hs + c4);
            fma4(a0, g.x, hv);
            fma4(a1, g.y, hv);
            fma4(a2, g.z, hv);
        }
        float inv = 1.0f / (float)max(dg, 1);
        float* Sr = S + (long)d * (3 * CINP);
        a0.x *= inv; a0.y *= inv; a0.z *= inv; a0.w *= inv;
        a1.x *= inv; a1.y *= inv; a1.z *= inv; a1.w *= inv;
        a2.x *= inv; a2.y *= inv; a2.z *= inv; a2.w *= inv;
        *(float4*)(Sr + c4)            = a0;
        *(float4*)(Sr + CINP + c4)     = a1;
        *(float4*)(Sr + 2 * CINP + c4) = a2;
    }
}

// ---------------- build Wc[4*CINP, 64] = [g0;g1;g2;root], zero-padded ----------------
template <int CIN, int CINP, int COUTR>
__global__ __launch_bounds__(256) void build_wc(const float* __restrict__ g,
                                                const float* __restrict__ root,
                                                float* __restrict__ Wc) {
    int t = blockIdx.x * 256 + threadIdx.x;
    constexpr int KTOT = 4 * CINP;
    if (t >= KTOT * 64) return;
    int kt = t >> 6, o = t & 63;
    int k = kt / CINP, c = kt % CINP;
    float v = 0.0f;
    if (c < CIN && o < COUTR)
        v = (k < 3) ? g[c * (3 * COUTR) + k * COUTR + o] : root[c * COUTR + o];
    Wc[t] = v;
}

// ---------------- row GEMM w/ LDS-staged A: out = relu([A|h] @ Wc + b) ----------------
// Block = 64 rows. Phase 1: coalesced stage of A-tile (64 x KA, contiguous) into LDS
// with odd-float4 row stride (conflict-free b128 reads). Phase 2: lane=row, wave=16-col
// strip, acc[16]/lane; W via wave-uniform s_load broadcast; h direct per-lane.
// NOTE: out must NOT alias h (two+ waves read the full h row per output row).
template <int KA, int KH>
__global__ __launch_bounds__(256, 2) void rowgemm_lds(const float* __restrict__ A,
                                                      const float* __restrict__ h, int hs,
                                                      const float* __restrict__ Wc,
                                                      const float* __restrict__ bias,
                                                      int coutr, float* __restrict__ out, int n) {
    constexpr int KA4 = KA / 4;
    constexpr int SA  = KA4 + 1;                 // odd float4 stride
    __shared__ float4 sa[64 * SA];
    const int row0 = blockIdx.x * 64;
    // ---- phase 1: stage 64 x KA tile (global-contiguous, coalesced) ----
    for (int f = threadIdx.x; f < 64 * KA4; f += 256) {
        int r = f / KA4, c4 = f % KA4;
        int gr = row0 + r; if (gr > n - 1) gr = n - 1;
        sa[r * SA + c4] = ((const float4*)(A + (long)gr * KA))[c4];
    }
    __syncthreads();
    // ---- phase 2 ----
    const int lane = threadIdx.x & 63;           // = local row
    const int wid  = __builtin_amdgcn_readfirstlane(threadIdx.x >> 6);
    const int cb   = wid * 16;                   // column base for this wave
    int row = row0 + lane;
    const bool valid = (row < n) && (cb < coutr);
    int rowc = (row < n) ? row : (n - 1);
    const float4* Hp = (const float4*)(h + (long)rowc * hs);
    float acc[16];
#pragma unroll
    for (int c = 0; c < 16; ++c) acc[c] = 0.0f;
#pragma unroll 2
    for (int k4 = 0; k4 < KA4; ++k4) {
        float4 a = sa[lane * SA + k4];
        float av[4] = {a.x, a.y, a.z, a.w};
#pragma unroll
        for (int j = 0; j < 4; ++j) {
            const float* wrow = Wc + (4 * k4 + j) * 64 + cb;   // wave-uniform -> s_load
#pragma unroll
            for (int c = 0; c < 16; ++c)
                acc[c] = fmaf(av[j], wrow[c], acc[c]);
        }
    }
#pragma unroll 2
    for (int k4 = 0; k4 < KH / 4; ++k4) {
        float4 a = Hp[k4];
        float av[4] = {a.x, a.y, a.z, a.w};
#pragma unroll
        for (int j = 0; j < 4; ++j) {
            const float* wrow = Wc + (KA + 4 * k4 + j) * 64 + cb;
#pragma unroll
            for (int c = 0; c < 16; ++c)
                acc[c] = fmaf(av[j], wrow[c], acc[c]);
        }
    }
    if (valid) {
        const float* bh = bias + cb;
        float4* o4 = (float4*)(out + (long)row * coutr + cb);
#pragma unroll
        for (int c4 = 0; c4 < 4; ++c4) {
            float4 v;
            v.x = fmaxf(acc[4 * c4 + 0] + bh[4 * c4 + 0], 0.0f);
            v.y = fmaxf(acc[4 * c4 + 1] + bh[4 * c4 + 1], 0.0f);
            v.z = fmaxf(acc[4 * c4 + 2] + bh[4 * c4 + 2], 0.0f);
            v.w = fmaxf(acc[4 * c4 + 3] + bh[4 * c4 + 3], 0.0f);
            o4[c4] = v;
        }
    }
}

// ---------------- final FC (64->2) + log_softmax ----------------
__global__ __launch_bounds__(256) void final_kernel(const float* __restrict__ h,
                                                    const float* __restrict__ fcw,
                                                    const float* __restrict__ fcb,
                                                    float* __restrict__ out, int n) {
    int i = blockIdx.x * 256 + threadIdx.x;
    if (i >= n) return;
    const float4* h4 = (const float4*)(h + (long)i * 64);
    float l0 = fcb[0];
    float l1 = fcb[1];
#pragma unroll
    for (int j4 = 0; j4 < 16; ++j4) {
        float4 hv = h4[j4];
        l0 = fmaf(hv.x, fcw[8 * j4 + 0], l0);
        l1 = fmaf(hv.x, fcw[8 * j4 + 1], l1);
        l0 = fmaf(hv.y, fcw[8 * j4 + 2], l0);
        l1 = fmaf(hv.y, fcw[8 * j4 + 3], l1);
        l0 = fmaf(hv.z, fcw[8 * j4 + 4], l0);
        l1 = fmaf(hv.z, fcw[8 * j4 + 5], l1);
        l0 = fmaf(hv.w, fcw[8 * j4 + 6], l0);
        l1 = fmaf(hv.w, fcw[8 * j4 + 7], l1);
    }
    float mx  = fmaxf(l0, l1);
    float lse = mx + logf(__expf(l0 - mx) + __expf(l1 - mx));
    out[2 * (long)i]     = l0 - lse;
    out[2 * (long)i + 1] = l1 - lse;
}

extern "C" void kernel_launch(void* const* d_in, const int* in_sizes, int n_in,
                              void* d_out, int out_size, void* d_ws, size_t ws_size,
                              hipStream_t stream) {
    const float* x   = (const float*)d_in[0];
    const int*   ei  = (const int*)d_in[1];
    const float* ea  = (const float*)d_in[2];
    const float* g_[3]  = {(const float*)d_in[3],  (const float*)d_in[8],  (const float*)d_in[13]};
    const float* mu_[3] = {(const float*)d_in[4],  (const float*)d_in[9],  (const float*)d_in[14]};
    const float* sg_[3] = {(const float*)d_in[5],  (const float*)d_in[10], (const float*)d_in[15]};
    const float* rt_[3] = {(const float*)d_in[6],  (const float*)d_in[11], (const float*)d_in[16]};
    const float* bs_[3] = {(const float*)d_in[7],  (const float*)d_in[12], (const float*)d_in[17]};
    const float* fcw = (const float*)d_in[18];
    const float* fcb = (const float*)d_in[19];
    float* out = (float*)d_out;
    (void)in_sizes; (void)n_in; (void)out_size; (void)ws_size;

    // workspace carve-up (~240 MB)
    char* w = (char*)d_ws;
    size_t off = 0;
    auto carve = [&](size_t bytes) -> void* {
        void* p = (void*)(w + off);
        off += (bytes + 255) & ~(size_t)255;
        return p;
    };
    int*    degi   = (int*)carve((size_t)NN * 4);
    int*    cursor = (int*)carve((size_t)NN * 4);
    int*    srcs   = (int*)carve((size_t)NE * 4);
    float2* eas2   = (float2*)carve((size_t)NE * 8);
    float4* gs4    = (float4*)carve((size_t)NE * 16);
    float*  S      = (float*)carve((size_t)NN * 192 * 4);   // A buffer, max 3*CINP=192
    int*    bsum   = (int*)carve(1024 * 4);
    float*  Wc     = (float*)carve((size_t)256 * 64 * 4);
    float*  xp     = (float*)carve((size_t)NN * 32 * 4);    // padded input [N,32]
    float*  hA     = (float*)carve((size_t)NN * 32 * 4);    // layer-0 out [N,32]
    float*  hB     = (float*)carve((size_t)NN * 64 * 4);    // layer-1 out [N,64]
    // xp/hA are adjacent 256-aligned carves (each a multiple of 256 B) forming a
    // contiguous [N,64] region that is dead after layer 1 -> reuse as layer-2 out.
    float*  hC     = xp;

    const int* src = ei;
    const int* dst = ei + NE;
    const int EB = (NE + 255) / 256;
    const int GB = (NN + 63) / 64;   // 2561 blocks: 64 rows per block

    // ---- CSR build (once per call) ----
    hipMemsetAsync(degi, 0, (size_t)NN * 4, stream);
    deg_count<<<EB, 256, 0, stream>>>(dst, degi, NE);
    scan1<<<NB, 256, 0, stream>>>(degi, cursor, bsum, NN);
    scan2<<<1, 1024, 0, stream>>>(bsum, NB);
    scan3<<<NB, 256, 0, stream>>>(cursor, bsum, NN);
    scatter_k<<<EB, 256, 0, stream>>>(src, dst, ea, cursor, srcs, eas2, NE);
    pad_x<<<(NN * 32 + 255) / 256, 256, 0, stream>>>(x, xp, NN);

    // ---- layer 0: 22(pad32) -> 32  (A = [N,96]) ----
    gauss_p<<<EB, 256, 0, stream>>>(eas2, mu_[0], sg_[0], gs4, NE);
    aggregate4<32><<<1024, 256, 0, stream>>>(xp, 32, srcs, gs4, cursor, degi, S, NN);
    build_wc<22, 32, 32><<<32, 256, 0, stream>>>(g_[0], rt_[0], Wc);
    rowgemm_lds<96, 32><<<GB, 256, 0, stream>>>(S, xp, 32, Wc, bs_[0], 32, hA, NN);

    // ---- layer 1: 32 -> 64  (A = [N,96]) ----
    gauss_p<<<EB, 256, 0, stream>>>(eas2, mu_[1], sg_[1], gs4, NE);
    aggregate4<32><<<1024, 256, 0, stream>>>(hA, 32, srcs, gs4, cursor, degi, S, NN);
    build_wc<32, 32, 64><<<32, 256, 0, stream>>>(g_[1], rt_[1], Wc);
    rowgemm_lds<96, 32><<<GB, 256, 0, stream>>>(S, hA, 32, Wc, bs_[1], 64, hB, NN);

    // ---- layer 2: 64 -> 64  (A = [N,192]; out -> hC, distinct from h=hB) ----
    gauss_p<<<EB, 256, 0, stream>>>(eas2, mu_[2], sg_[2], gs4, NE);
    aggregate4<64><<<2048, 256, 0, stream>>>(hB, 64, srcs, gs4, cursor, degi, S, NN);
    build_wc<64, 64, 64><<<64, 256, 0, stream>>>(g_[2], rt_[2], Wc);
    rowgemm_lds<192, 64><<<GB, 256, 0, stream>>>(S, hB, 64, Wc, bs_[2], 64, hC, NN);

    final_kernel<<<(NN + 255) / 256, 256, 0, stream>>>(hC, fcw, fcb, out, NN);
}

// Round 10
// 542.580 us; speedup vs baseline: 1.0695x; 1.0695x over previous
//
#include <hip/hip_runtime.h>

#define NN 163842
#define NE 983040
#define NB 641   // ceil(NN/256)

// ---------------- degree count (int) ----------------
__global__ __launch_bounds__(256) void deg_count(const int* __restrict__ dst,
                                                 int* __restrict__ degi, int E) {
    int e = blockIdx.x * 256 + threadIdx.x;
    if (e < E) atomicAdd(&degi[dst[e]], 1);
}

// ---------------- exclusive scan of degi -> cursor ----------------
__global__ __launch_bounds__(256) void scan1(const int* __restrict__ degi,
                                             int* __restrict__ cursor,
                                             int* __restrict__ bsum, int n) {
    __shared__ int tmp[256];
    int t = threadIdx.x;
    int i = blockIdx.x * 256 + t;
    int v = (i < n) ? degi[i] : 0;
    tmp[t] = v;
    __syncthreads();
    for (int o = 1; o < 256; o <<= 1) {
        int x = (t >= o) ? tmp[t - o] : 0;
        __syncthreads();
        tmp[t] += x;
        __syncthreads();
    }
    if (i < n) cursor[i] = tmp[t] - v;            // exclusive
    if (t == 255) bsum[blockIdx.x] = tmp[255];    // block total
}

__global__ void scan2(int* __restrict__ bsum, int nb) {
    __shared__ int tmp[1024];
    int t = threadIdx.x;
    int v = (t < nb) ? bsum[t] : 0;
    tmp[t] = v;
    __syncthreads();
    for (int o = 1; o < 1024; o <<= 1) {
        int x = (t >= o) ? tmp[t - o] : 0;
        __syncthreads();
        tmp[t] += x;
        __syncthreads();
    }
    if (t < nb) bsum[t] = tmp[t] - v;
}

__global__ __launch_bounds__(256) void scan3(int* __restrict__ cursor,
                                             const int* __restrict__ bsum, int n) {
    int i = blockIdx.x * 256 + threadIdx.x;
    if (i < n) cursor[i] += bsum[blockIdx.x];
}

// ---------------- scatter: permute src / edge_attr into dst-sorted order ----------------
__global__ __launch_bounds__(256) void scatter_k(const int* __restrict__ src,
                                                 const int* __restrict__ dst,
                                                 const float* __restrict__ ea,
                                                 int* __restrict__ cursor,
                                                 int* __restrict__ srcs,
                                                 float2* __restrict__ eas2, int E) {
    int e = blockIdx.x * 256 + threadIdx.x;
    if (e >= E) return;
    int p = atomicAdd(&cursor[dst[e]], 1);
    srcs[p] = src[e];
    eas2[p] = make_float2(ea[2 * e], ea[2 * e + 1]);
}

// ---------------- pad x [N,22] -> xp [N,32] ----------------
__global__ __launch_bounds__(256) void pad_x(const float* __restrict__ x,
                                             float* __restrict__ xp, int n) {
    int t = blockIdx.x * 256 + threadIdx.x;
    if (t >= n * 32) return;
    int r = t >> 5, c = t & 31;
    xp[t] = (c < 22) ? x[r * 22 + c] : 0.0f;
}

// ---------------- gaussians (permuted order), packed float4 ----------------
__global__ __launch_bounds__(256) void gauss_p(const float2* __restrict__ eas2,
                                               const float* __restrict__ mu,
                                               const float* __restrict__ sigma,
                                               float4* __restrict__ gs4, int E) {
    int p = blockIdx.x * 256 + threadIdx.x;
    if (p >= E) return;
    float2 ea = eas2[p];
    float g[3];
#pragma unroll
    for (int k = 0; k < 3; ++k) {
        float d0 = ea.x - mu[2 * k];
        float d1 = ea.y - mu[2 * k + 1];
        float s0 = sigma[2 * k];
        float s1 = sigma[2 * k + 1];
        float q  = d0 * d0 / (1e-15f + s0 * s0) + d1 * d1 / (1e-15f + s1 * s1);
        g[k] = __expf(-0.5f * q);
    }
    gs4[p] = make_float4(g[0], g[1], g[2], 0.0f);
}

static __device__ __forceinline__ void fma4(float4& a, float g, const float4& hv) {
    a.x = fmaf(g, hv.x, a.x);
    a.y = fmaf(g, hv.y, a.y);
    a.z = fmaf(g, hv.z, a.z);
    a.w = fmaf(g, hv.w, a.w);
}

// ---------------- dst-centric segmented aggregation (no atomics, float4, 4x unroll) ----
template <int CINP>
__global__ __launch_bounds__(256) void aggregate4(const float* __restrict__ h, int hs,
                                                  const int* __restrict__ srcs,
                                                  const float4* __restrict__ gs4,
                                                  const int* __restrict__ cursor,
                                                  const int* __restrict__ degi,
                                                  float* __restrict__ S, int n) {
    constexpr int LPN = CINP / 4;                     // lanes per node
    const int c4 = (threadIdx.x % LPN) * 4;
    const int sw = (blockIdx.x * 256 + threadIdx.x) / LPN;
    const int nsw = gridDim.x * (256 / LPN);
    for (int d = sw; d < n; d += nsw) {
        int end = cursor[d];
        int dg  = degi[d];
        int p   = end - dg;
        float4 a0 = {0, 0, 0, 0}, a1 = {0, 0, 0, 0}, a2 = {0, 0, 0, 0};
        for (; p + 4 <= end; p += 4) {
            int s[4];
            float4 g[4], hv[4];
#pragma unroll
            for (int u = 0; u < 4; ++u) s[u] = srcs[p + u];
#pragma unroll
            for (int u = 0; u < 4; ++u) g[u] = gs4[p + u];
#pragma unroll
            for (int u = 0; u < 4; ++u)
                hv[u] = *(const float4*)(h + (long)s[u] * hs + c4);
#pragma unroll
            for (int u = 0; u < 4; ++u) {
                fma4(a0, g[u].x, hv[u]);
                fma4(a1, g[u].y, hv[u]);
                fma4(a2, g[u].z, hv[u]);
            }
        }
        for (; p < end; ++p) {
            int s = srcs[p];
            float4 g = gs4[p];
            float4 hv = *(const float4*)(h + (long)s * hs + c4);
            fma4(a0, g.x, hv);
            fma4(a1, g.y, hv);
            fma4(a2, g.z, hv);
        }
        float inv = 1.0f / (float)max(dg, 1);
        float* Sr = S + (long)d * (3 * CINP);
        a0.x *= inv; a0.y *= inv; a0.z *= inv; a0.w *= inv;
        a1.x *= inv; a1.y *= inv; a1.z *= inv; a1.w *= inv;
        a2.x *= inv; a2.y *= inv; a2.z *= inv; a2.w *= inv;
        *(float4*)(Sr + c4)            = a0;
        *(float4*)(Sr + CINP + c4)     = a1;
        *(float4*)(Sr + 2 * CINP + c4) = a2;
    }
}

// ---------------- build Wc[4*CINP, 64] = [g0;g1;g2;root], zero-padded ----------------
template <int CIN, int CINP, int COUTR>
__global__ __launch_bounds__(256) void build_wc(const float* __restrict__ g,
                                                const float* __restrict__ root,
                                                float* __restrict__ Wc) {
    int t = blockIdx.x * 256 + threadIdx.x;
    constexpr int KTOT = 4 * CINP;
    if (t >= KTOT * 64) return;
    int kt = t >> 6, o = t & 63;
    int k = kt / CINP, c = kt % CINP;
    float v = 0.0f;
    if (c < CIN && o < COUTR)
        v = (k < 3) ? g[c * (3 * COUTR) + k * COUTR + o] : root[c * COUTR + o];
    Wc[t] = v;
}

// ---------------- row GEMM, K-chunked LDS staging: out = relu([A|h] @ Wc + b) -------
// Block = 64 rows. K processed in chunks of <=96 floats (24 float4): each chunk is
// cooperatively staged into a 64x25-float4 LDS tile (25.6 KB -> 6 blocks/CU), then
// lane=row / wave=16-col-strip accumulates from LDS; W rows are wave-uniform s_load
// broadcasts. acc[16] lives in registers across chunk barriers. Odd float4 stride 25
// -> conflict-free ds_read_b128 (25r mod 8 cycles all bank groups).
// NOTE: out must NOT alias h (multiple waves read the full h row per output row).
template <int KA, int KH>
__global__ __launch_bounds__(256) void rowgemm_c(const float* __restrict__ A,
                                                 const float* __restrict__ h, int hs,
                                                 const float* __restrict__ Wc,
                                                 const float* __restrict__ bias,
                                                 int coutr, float* __restrict__ out, int n) {
    constexpr int KA4 = KA / 4;
    constexpr int KH4 = KH / 4;
    constexpr int C4  = 24;                      // float4 per chunk (96 floats)
    constexpr int NCH = KA4 / C4;                // A chunks (KA4 % 24 == 0)
    __shared__ float4 sa[64 * 25];
    const int row0 = blockIdx.x * 64;
    const int lane = threadIdx.x & 63;           // local row
    const int wid  = __builtin_amdgcn_readfirstlane(threadIdx.x >> 6);
    const int cb   = wid * 16;                   // column strip base
    int row = row0 + lane;
    const bool valid = (row < n) && (cb < coutr);
    int rowc = (row < n) ? row : (n - 1);
    float acc[16];
#pragma unroll
    for (int c = 0; c < 16; ++c) acc[c] = 0.0f;

#pragma unroll
    for (int ch = 0; ch < NCH; ++ch) {
        // stage chunk: rows r, float4 cols [ch*C4, ch*C4+C4)
        __syncthreads();
        for (int f = threadIdx.x; f < 64 * C4; f += 256) {
            int r = f / C4, c4 = f % C4;
            int gr = row0 + r; if (gr > n - 1) gr = n - 1;
            sa[r * 25 + c4] = ((const float4*)(A + (long)gr * KA))[ch * C4 + c4];
        }
        __syncthreads();
#pragma unroll 2
        for (int k4 = 0; k4 < C4; ++k4) {
            float4 a = sa[lane * 25 + k4];
            float av[4] = {a.x, a.y, a.z, a.w};
#pragma unroll
            for (int j = 0; j < 4; ++j) {
                const float* wrow = Wc + ((ch * C4 + k4) * 4 + j) * 64 + cb;  // s_load
#pragma unroll
                for (int c = 0; c < 16; ++c)
                    acc[c] = fmaf(av[j], wrow[c], acc[c]);
            }
        }
    }
    // h chunk (KH4 <= 24)
    __syncthreads();
    for (int f = threadIdx.x; f < 64 * KH4; f += 256) {
        int r = f / KH4, c4 = f % KH4;
        int gr = row0 + r; if (gr > n - 1) gr = n - 1;
        sa[r * 25 + c4] = ((const float4*)(h + (long)gr * hs))[c4];
    }
    __syncthreads();
#pragma unroll 2
    for (int k4 = 0; k4 < KH4; ++k4) {
        float4 a = sa[lane * 25 + k4];
        float av[4] = {a.x, a.y, a.z, a.w};
#pragma unroll
        for (int j = 0; j < 4; ++j) {
            const float* wrow = Wc + ((KA4 + k4) * 4 + j) * 64 + cb;
#pragma unroll
            for (int c = 0; c < 16; ++c)
                acc[c] = fmaf(av[j], wrow[c], acc[c]);
        }
    }
    if (valid) {
        const float* bh = bias + cb;
        float4* o4 = (float4*)(out + (long)row * coutr + cb);
#pragma unroll
        for (int c4 = 0; c4 < 4; ++c4) {
            float4 v;
            v.x = fmaxf(acc[4 * c4 + 0] + bh[4 * c4 + 0], 0.0f);
            v.y = fmaxf(acc[4 * c4 + 1] + bh[4 * c4 + 1], 0.0f);
            v.z = fmaxf(acc[4 * c4 + 2] + bh[4 * c4 + 2], 0.0f);
            v.w = fmaxf(acc[4 * c4 + 3] + bh[4 * c4 + 3], 0.0f);
            o4[c4] = v;
        }
    }
}

// ---------------- final FC (64->2) + log_softmax ----------------
__global__ __launch_bounds__(256) void final_kernel(const float* __restrict__ h,
                                                    const float* __restrict__ fcw,
                                                    const float* __restrict__ fcb,
                                                    float* __restrict__ out, int n) {
    int i = blockIdx.x * 256 + threadIdx.x;
    if (i >= n) return;
    const float4* h4 = (const float4*)(h + (long)i * 64);
    float l0 = fcb[0];
    float l1 = fcb[1];
#pragma unroll
    for (int j4 = 0; j4 < 16; ++j4) {
        float4 hv = h4[j4];
        l0 = fmaf(hv.x, fcw[8 * j4 + 0], l0);
        l1 = fmaf(hv.x, fcw[8 * j4 + 1], l1);
        l0 = fmaf(hv.y, fcw[8 * j4 + 2], l0);
        l1 = fmaf(hv.y, fcw[8 * j4 + 3], l1);
        l0 = fmaf(hv.z, fcw[8 * j4 + 4], l0);
        l1 = fmaf(hv.z, fcw[8 * j4 + 5], l1);
        l0 = fmaf(hv.w, fcw[8 * j4 + 6], l0);
        l1 = fmaf(hv.w, fcw[8 * j4 + 7], l1);
    }
    float mx  = fmaxf(l0, l1);
    float lse = mx + logf(__expf(l0 - mx) + __expf(l1 - mx));
    out[2 * (long)i]     = l0 - lse;
    out[2 * (long)i + 1] = l1 - lse;
}

extern "C" void kernel_launch(void* const* d_in, const int* in_sizes, int n_in,
                              void* d_out, int out_size, void* d_ws, size_t ws_size,
                              hipStream_t stream) {
    const float* x   = (const float*)d_in[0];
    const int*   ei  = (const int*)d_in[1];
    const float* ea  = (const float*)d_in[2];
    const float* g_[3]  = {(const float*)d_in[3],  (const float*)d_in[8],  (const float*)d_in[13]};
    const float* mu_[3] = {(const float*)d_in[4],  (const float*)d_in[9],  (const float*)d_in[14]};
    const float* sg_[3] = {(const float*)d_in[5],  (const float*)d_in[10], (const float*)d_in[15]};
    const float* rt_[3] = {(const float*)d_in[6],  (const float*)d_in[11], (const float*)d_in[16]};
    const float* bs_[3] = {(const float*)d_in[7],  (const float*)d_in[12], (const float*)d_in[17]};
    const float* fcw = (const float*)d_in[18];
    const float* fcb = (const float*)d_in[19];
    float* out = (float*)d_out;
    (void)in_sizes; (void)n_in; (void)out_size; (void)ws_size;

    // workspace carve-up (~240 MB)
    char* w = (char*)d_ws;
    size_t off = 0;
    auto carve = [&](size_t bytes) -> void* {
        void* p = (void*)(w + off);
        off += (bytes + 255) & ~(size_t)255;
        return p;
    };
    int*    degi   = (int*)carve((size_t)NN * 4);
    int*    cursor = (int*)carve((size_t)NN * 4);
    int*    srcs   = (int*)carve((size_t)NE * 4);
    float2* eas2   = (float2*)carve((size_t)NE * 8);
    float4* gs4    = (float4*)carve((size_t)NE * 16);
    float*  S      = (float*)carve((size_t)NN * 192 * 4);   // A buffer, max 3*CINP=192
    int*    bsum   = (int*)carve(1024 * 4);
    float*  Wc     = (float*)carve((size_t)256 * 64 * 4);
    float*  xp     = (float*)carve((size_t)NN * 32 * 4);    // padded input [N,32]
    float*  hA     = (float*)carve((size_t)NN * 32 * 4);    // layer-0 out [N,32]
    float*  hB     = (float*)carve((size_t)NN * 64 * 4);    // layer-1 out [N,64]
    // xp/hA are adjacent 256-aligned carves (each a multiple of 256 B) forming a
    // contiguous [N,64] region that is dead after layer 1 -> reuse as layer-2 out.
    float*  hC     = xp;

    const int* src = ei;
    const int* dst = ei + NE;
    const int EB = (NE + 255) / 256;
    const int GB = (NN + 63) / 64;   // 2561 blocks: 64 rows per block

    // ---- CSR build (once per call) ----
    hipMemsetAsync(degi, 0, (size_t)NN * 4, stream);
    deg_count<<<EB, 256, 0, stream>>>(dst, degi, NE);
    scan1<<<NB, 256, 0, stream>>>(degi, cursor, bsum, NN);
    scan2<<<1, 1024, 0, stream>>>(bsum, NB);
    scan3<<<NB, 256, 0, stream>>>(cursor, bsum, NN);
    scatter_k<<<EB, 256, 0, stream>>>(src, dst, ea, cursor, srcs, eas2, NE);
    pad_x<<<(NN * 32 + 255) / 256, 256, 0, stream>>>(x, xp, NN);

    // ---- layer 0: 22(pad32) -> 32  (A = [N,96]) ----
    gauss_p<<<EB, 256, 0, stream>>>(eas2, mu_[0], sg_[0], gs4, NE);
    aggregate4<32><<<1024, 256, 0, stream>>>(xp, 32, srcs, gs4, cursor, degi, S, NN);
    build_wc<22, 32, 32><<<32, 256, 0, stream>>>(g_[0], rt_[0], Wc);
    rowgemm_c<96, 32><<<GB, 256, 0, stream>>>(S, xp, 32, Wc, bs_[0], 32, hA, NN);

    // ---- layer 1: 32 -> 64  (A = [N,96]) ----
    gauss_p<<<EB, 256, 0, stream>>>(eas2, mu_[1], sg_[1], gs4, NE);
    aggregate4<32><<<1024, 256, 0, stream>>>(hA, 32, srcs, gs4, cursor, degi, S, NN);
    build_wc<32, 32, 64><<<32, 256, 0, stream>>>(g_[1], rt_[1], Wc);
    rowgemm_c<96, 32><<<GB, 256, 0, stream>>>(S, hA, 32, Wc, bs_[1], 64, hB, NN);

    // ---- layer 2: 64 -> 64  (A = [N,192]; out -> hC, distinct from h=hB) ----
    gauss_p<<<EB, 256, 0, stream>>>(eas2, mu_[2], sg_[2], gs4, NE);
    aggregate4<64><<<2048, 256, 0, stream>>>(hB, 64, srcs, gs4, cursor, degi, S, NN);
    build_wc<64, 64, 64><<<64, 256, 0, stream>>>(g_[2], rt_[2], Wc);
    rowgemm_c<192, 64><<<GB, 256, 0, stream>>>(S, hB, 64, Wc, bs_[2], 64, hC, NN);

    final_kernel<<<(NN + 255) / 256, 256, 0, stream>>>(hC, fcw, fcb, out, NN);
}